// Round 1
// baseline (370.376 us; speedup 1.0000x reference)
//
#include <hip/hip_runtime.h>

#define HIDDEN 128
#define P_NUM 8
#define PLEN 4
#define ETYPES 2
#define BN 64                      // nodes per block
#define APAD 8                     // bf16 pad per A row (breaks LDS bank conflicts)
#define AROW (2*HIDDEN + APAD)     // 264 bf16 = 528 B row stride

typedef __attribute__((ext_vector_type(8))) short short8;
typedef __attribute__((ext_vector_type(4))) float floatx4;

__device__ __forceinline__ unsigned short f2bf(float x) {
  unsigned int u = __float_as_uint(x);
  u += 0x7FFFu + ((u >> 16) & 1u);   // round-to-nearest-even
  return (unsigned short)(u >> 16);
}

__global__ __launch_bounds__(256, 3) void impeller_fused(
    const float* __restrict__ feats,
    const int* __restrict__ paths,
    const int* __restrict__ ptypes,
    const float* __restrict__ pweights,
    const float* __restrict__ Wfc,
    float* __restrict__ out,
    int n_nodes)
{
  __shared__ __align__(16) unsigned short A[BN * AROW];   // 33792 B: fout tile, bf16
  __shared__ int idx_lds[P_NUM * BN * PLEN];              // 8192 B
  __shared__ float2 cw[P_NUM * PLEN];                     // 256 B: per-(p,l) weights for (acc0, acc1)

  const int tid = threadIdx.x;
  const int n0 = blockIdx.x * BN;

  // ---- stage this block's path indices (coalesced: 256 contiguous ints per p) ----
  #pragma unroll
  for (int p = 0; p < P_NUM; ++p) {
    int g = n0 * PLEN + tid;
    int v = 0;
    if (g < n_nodes * PLEN) v = paths[(size_t)p * n_nodes * PLEN + g];
    idx_lds[p * (BN * PLEN) + tid] = v;
  }

  // ---- combined weights: cw[p][l] = (w[type,l]/cnt_type) routed to acc0 or acc1 ----
  if (tid < P_NUM * PLEN) {
    int p = tid >> 2, l = tid & 3;
    int cnt0 = 0;
    #pragma unroll
    for (int q = 0; q < P_NUM; ++q) cnt0 += (ptypes[q] == 0);
    int cnt1 = P_NUM - cnt0;
    int t = ptypes[p];
    float w = pweights[t * PLEN + l];
    float2 c;
    c.x = (t == 0) ? w / (float)cnt0 : 0.f;
    c.y = (t == 1) ? w / (float)cnt1 : 0.f;
    cw[tid] = c;
  }
  __syncthreads();

  // ---- gather + weighted sum: 8 nodes at a time (32 threads/node, 4 dims/thread) ----
  const int ng = tid >> 5;          // node slot 0..7
  const int d4 = (tid & 31) * 4;    // feature dims [d4, d4+4)
  #pragma unroll 1
  for (int it = 0; it < BN / 8; ++it) {
    const int nl = it * 8 + ng;
    float a0x = 0.f, a0y = 0.f, a0z = 0.f, a0w = 0.f;
    float a1x = 0.f, a1y = 0.f, a1z = 0.f, a1w = 0.f;
    #pragma unroll
    for (int p = 0; p < P_NUM; ++p) {
      #pragma unroll
      for (int l = 0; l < PLEN; ++l) {
        int idx = idx_lds[p * (BN * PLEN) + nl * PLEN + l];   // LDS broadcast
        float2 c = cw[p * PLEN + l];
        const float4 f = *(const float4*)(feats + (size_t)idx * HIDDEN + d4);
        a0x += c.x * f.x; a0y += c.x * f.y; a0z += c.x * f.z; a0w += c.x * f.w;
        a1x += c.y * f.x; a1y += c.y * f.y; a1z += c.y * f.z; a1w += c.y * f.w;
      }
    }
    ushort4 u0 = make_ushort4(f2bf(a0x), f2bf(a0y), f2bf(a0z), f2bf(a0w));
    ushort4 u1 = make_ushort4(f2bf(a1x), f2bf(a1y), f2bf(a1z), f2bf(a1w));
    *(ushort4*)&A[nl * AROW + d4] = u0;            // fout[:, 0:128]   (type-0 mean)
    *(ushort4*)&A[nl * AROW + HIDDEN + d4] = u1;   // fout[:, 128:256] (type-1 mean)
  }
  __syncthreads();

  // ---- MFMA GEMM: out(64x128) = A(64x256) @ Wfc^T(256x128), 16x16x32 bf16 ----
  const int wid = tid >> 6;         // wave 0..3 -> output cols [wid*32, wid*32+32)
  const int lane = tid & 63;
  const int q = lane >> 4;          // quad 0..3
  const int r = lane & 15;

  floatx4 acc[4][2];
  #pragma unroll
  for (int mt = 0; mt < 4; ++mt)
    #pragma unroll
    for (int jt = 0; jt < 2; ++jt)
      acc[mt][jt] = (floatx4){0.f, 0.f, 0.f, 0.f};

  #pragma unroll
  for (int kk = 0; kk < 8; ++kk) {
    short8 af[4];
    #pragma unroll
    for (int mt = 0; mt < 4; ++mt)
      af[mt] = *(const short8*)&A[(mt * 16 + r) * AROW + kk * 32 + q * 8];

    short8 bf[2];
    #pragma unroll
    for (int jt = 0; jt < 2; ++jt) {
      const int j = wid * 32 + jt * 16 + r;                   // output col = Wfc row
      const float* wp = Wfc + (size_t)j * (ETYPES * HIDDEN) + kk * 32 + q * 8;
      const float4 wa = *(const float4*)wp;
      const float4 wb = *(const float4*)(wp + 4);
      short8 b;
      b[0] = (short)f2bf(wa.x); b[1] = (short)f2bf(wa.y);
      b[2] = (short)f2bf(wa.z); b[3] = (short)f2bf(wa.w);
      b[4] = (short)f2bf(wb.x); b[5] = (short)f2bf(wb.y);
      b[6] = (short)f2bf(wb.z); b[7] = (short)f2bf(wb.w);
      bf[jt] = b;
    }

    #pragma unroll
    for (int mt = 0; mt < 4; ++mt)
      #pragma unroll
      for (int jt = 0; jt < 2; ++jt)
        acc[mt][jt] = __builtin_amdgcn_mfma_f32_16x16x32_bf16(af[mt], bf[jt], acc[mt][jt], 0, 0, 0);
  }

  // ---- epilogue: relu + store. D layout: col = lane&15, row = q*4 + reg ----
  #pragma unroll
  for (int mt = 0; mt < 4; ++mt) {
    const int node_base = n0 + mt * 16 + q * 4;
    #pragma unroll
    for (int jt = 0; jt < 2; ++jt) {
      const int j = wid * 32 + jt * 16 + r;
      #pragma unroll
      for (int reg = 0; reg < 4; ++reg) {
        const int nn = node_base + reg;
        if (nn < n_nodes) out[(size_t)nn * HIDDEN + j] = fmaxf(acc[mt][jt][reg], 0.f);
      }
    }
  }
}

extern "C" void kernel_launch(void* const* d_in, const int* in_sizes, int n_in,
                              void* d_out, int out_size, void* d_ws, size_t ws_size,
                              hipStream_t stream) {
  const float* feats    = (const float*)d_in[0];
  const int*   paths    = (const int*)d_in[1];
  const int*   ptypes   = (const int*)d_in[2];
  const float* pweights = (const float*)d_in[3];
  const float* Wfc      = (const float*)d_in[4];
  float* out = (float*)d_out;

  const int n_nodes = in_sizes[0] / HIDDEN;
  const int blocks = (n_nodes + BN - 1) / BN;
  hipLaunchKernelGGL(impeller_fused, dim3(blocks), dim3(256), 0, stream,
                     feats, paths, ptypes, pweights, Wfc, out, n_nodes);
}

// Round 2
// 301.360 us; speedup vs baseline: 1.2290x; 1.2290x over previous
//
#include <hip/hip_runtime.h>

#define HIDDEN 128
#define P_NUM 8
#define PLEN 4
#define ETYPES 2
#define BN 64                      // nodes per block
#define APAD 8                     // bf16 pad per A row (breaks LDS bank conflicts)
#define AROW (2*HIDDEN + APAD)     // 264 bf16 = 528 B row stride

typedef __attribute__((ext_vector_type(8))) short short8;
typedef __attribute__((ext_vector_type(4))) float floatx4;

__device__ __forceinline__ unsigned short f2bf(float x) {
  unsigned int u = __float_as_uint(x);
  u += 0x7FFFu + ((u >> 16) & 1u);   // round-to-nearest-even
  return (unsigned short)(u >> 16);
}
__device__ __forceinline__ float bf2f(unsigned short u) {
  return __uint_as_float(((unsigned int)u) << 16);
}

// ---- feats f32 -> bf16 into workspace (one-shot, BW-bound ~12us) ----
__global__ __launch_bounds__(256) void cvt_bf16(const float* __restrict__ in,
                                                unsigned short* __restrict__ out, int n4) {
  int i = blockIdx.x * blockDim.x + threadIdx.x;
  if (i < n4) {
    float4 f = ((const float4*)in)[i];
    ushort4 u = make_ushort4(f2bf(f.x), f2bf(f.y), f2bf(f.z), f2bf(f.w));
    ((ushort4*)out)[i] = u;
  }
}

template<bool BF>
__global__ __launch_bounds__(256, 3) void impeller_fused(
    const void* __restrict__ feats_v,
    const int* __restrict__ paths,
    const int* __restrict__ ptypes,
    const float* __restrict__ pweights,
    const float* __restrict__ Wfc,
    float* __restrict__ out,
    int n_nodes)
{
  __shared__ __align__(16) unsigned short A[BN * AROW];   // 33792 B: fout tile, bf16
  __shared__ int idx_lds[P_NUM * BN * PLEN];              // 8192 B
  __shared__ float2 cw[P_NUM * PLEN];                     // 256 B

  const int tid = threadIdx.x;
  const int n0 = blockIdx.x * BN;

  // ---- stage this block's path indices (coalesced) ----
  #pragma unroll
  for (int p = 0; p < P_NUM; ++p) {
    int g = n0 * PLEN + tid;
    int v = 0;
    if (g < n_nodes * PLEN) v = paths[(size_t)p * n_nodes * PLEN + g];
    idx_lds[p * (BN * PLEN) + tid] = v;
  }

  // ---- combined weights: route w[type,l]/cnt_type to acc0 (type0) / acc1 (type1) ----
  if (tid < P_NUM * PLEN) {
    int p = tid >> 2, l = tid & 3;
    int cnt0 = 0;
    #pragma unroll
    for (int q = 0; q < P_NUM; ++q) cnt0 += (ptypes[q] == 0);
    int cnt1 = P_NUM - cnt0;
    int t = ptypes[p];
    float w = pweights[t * PLEN + l];
    float2 c;
    c.x = (t == 0) ? w / (float)cnt0 : 0.f;
    c.y = (t == 1) ? w / (float)cnt1 : 0.f;
    cw[tid] = c;
  }
  __syncthreads();

  // ---- gather + weighted sum: 8 nodes at a time (32 threads/node, 4 dims/thread) ----
  const int ng = tid >> 5;          // node slot 0..7
  const int d4 = (tid & 31) * 4;    // feature dims [d4, d4+4)
  #pragma unroll 1
  for (int it = 0; it < BN / 8; ++it) {
    const int nl = it * 8 + ng;
    float a0x = 0.f, a0y = 0.f, a0z = 0.f, a0w = 0.f;
    float a1x = 0.f, a1y = 0.f, a1z = 0.f, a1w = 0.f;
    #pragma unroll
    for (int p = 0; p < P_NUM; ++p) {
      #pragma unroll
      for (int l = 0; l < PLEN; ++l) {
        int idx = idx_lds[p * (BN * PLEN) + nl * PLEN + l];   // LDS broadcast
        float2 c = cw[p * PLEN + l];
        float fx, fy, fz, fw;
        if (BF) {
          const ushort4 fu = *(const ushort4*)((const unsigned short*)feats_v + (size_t)idx * HIDDEN + d4);
          fx = bf2f(fu.x); fy = bf2f(fu.y); fz = bf2f(fu.z); fw = bf2f(fu.w);
        } else {
          const float4 f = *(const float4*)((const float*)feats_v + (size_t)idx * HIDDEN + d4);
          fx = f.x; fy = f.y; fz = f.z; fw = f.w;
        }
        a0x += c.x * fx; a0y += c.x * fy; a0z += c.x * fz; a0w += c.x * fw;
        a1x += c.y * fx; a1y += c.y * fy; a1z += c.y * fz; a1w += c.y * fw;
      }
    }
    ushort4 u0 = make_ushort4(f2bf(a0x), f2bf(a0y), f2bf(a0z), f2bf(a0w));
    ushort4 u1 = make_ushort4(f2bf(a1x), f2bf(a1y), f2bf(a1z), f2bf(a1w));
    *(ushort4*)&A[nl * AROW + d4] = u0;            // fout[:, 0:128]
    *(ushort4*)&A[nl * AROW + HIDDEN + d4] = u1;   // fout[:, 128:256]
  }
  __syncthreads();

  // ---- MFMA GEMM: out(64x128) = A(64x256) @ Wfc^T(256x128), 16x16x32 bf16 ----
  const int wid = tid >> 6;
  const int lane = tid & 63;
  const int q = lane >> 4;
  const int r = lane & 15;

  floatx4 acc[4][2];
  #pragma unroll
  for (int mt = 0; mt < 4; ++mt)
    #pragma unroll
    for (int jt = 0; jt < 2; ++jt)
      acc[mt][jt] = (floatx4){0.f, 0.f, 0.f, 0.f};

  #pragma unroll
  for (int kk = 0; kk < 8; ++kk) {
    short8 af[4];
    #pragma unroll
    for (int mt = 0; mt < 4; ++mt)
      af[mt] = *(const short8*)&A[(mt * 16 + r) * AROW + kk * 32 + q * 8];

    short8 bf[2];
    #pragma unroll
    for (int jt = 0; jt < 2; ++jt) {
      const int j = wid * 32 + jt * 16 + r;                   // output col = Wfc row
      const float* wp = Wfc + (size_t)j * (ETYPES * HIDDEN) + kk * 32 + q * 8;
      const float4 wa = *(const float4*)wp;
      const float4 wb = *(const float4*)(wp + 4);
      short8 b;
      b[0] = (short)f2bf(wa.x); b[1] = (short)f2bf(wa.y);
      b[2] = (short)f2bf(wa.z); b[3] = (short)f2bf(wa.w);
      b[4] = (short)f2bf(wb.x); b[5] = (short)f2bf(wb.y);
      b[6] = (short)f2bf(wb.z); b[7] = (short)f2bf(wb.w);
      bf[jt] = b;
    }

    #pragma unroll
    for (int mt = 0; mt < 4; ++mt)
      #pragma unroll
      for (int jt = 0; jt < 2; ++jt)
        acc[mt][jt] = __builtin_amdgcn_mfma_f32_16x16x32_bf16(af[mt], bf[jt], acc[mt][jt], 0, 0, 0);
  }

  // ---- epilogue: relu + store. D layout: col = lane&15, row = q*4 + reg ----
  #pragma unroll
  for (int mt = 0; mt < 4; ++mt) {
    const int node_base = n0 + mt * 16 + q * 4;
    #pragma unroll
    for (int jt = 0; jt < 2; ++jt) {
      const int j = wid * 32 + jt * 16 + r;
      #pragma unroll
      for (int reg = 0; reg < 4; ++reg) {
        const int nn = node_base + reg;
        if (nn < n_nodes) out[(size_t)nn * HIDDEN + j] = fmaxf(acc[mt][jt][reg], 0.f);
      }
    }
  }
}

extern "C" void kernel_launch(void* const* d_in, const int* in_sizes, int n_in,
                              void* d_out, int out_size, void* d_ws, size_t ws_size,
                              hipStream_t stream) {
  const float* feats    = (const float*)d_in[0];
  const int*   paths    = (const int*)d_in[1];
  const int*   ptypes   = (const int*)d_in[2];
  const float* pweights = (const float*)d_in[3];
  const float* Wfc      = (const float*)d_in[4];
  float* out = (float*)d_out;

  const int n_nodes = in_sizes[0] / HIDDEN;
  const int blocks = (n_nodes + BN - 1) / BN;
  const size_t need = (size_t)in_sizes[0] * sizeof(unsigned short);

  if (ws_size >= need) {
    unsigned short* feats_bf = (unsigned short*)d_ws;
    const int n4 = in_sizes[0] / 4;
    hipLaunchKernelGGL(cvt_bf16, dim3((n4 + 255) / 256), dim3(256), 0, stream,
                       feats, feats_bf, n4);
    hipLaunchKernelGGL((impeller_fused<true>), dim3(blocks), dim3(256), 0, stream,
                       (const void*)feats_bf, paths, ptypes, pweights, Wfc, out, n_nodes);
  } else {
    hipLaunchKernelGGL((impeller_fused<false>), dim3(blocks), dim3(256), 0, stream,
                       (const void*)feats, paths, ptypes, pweights, Wfc, out, n_nodes);
  }
}